// Round 1
// baseline (3979.908 us; speedup 1.0000x reference)
//
#include <hip/hip_runtime.h>

#define NU 200000
#define NM 100000
#define NE 4000000
#define D  64

// ---------------------------------------------------------------------------
// degree (edge counts per destination) — identical for both layers
// ---------------------------------------------------------------------------
__global__ __launch_bounds__(256) void degree_k(const int* __restrict__ uidx,
                                                const int* __restrict__ midx,
                                                float* __restrict__ deg_u,
                                                float* __restrict__ deg_m) {
  int stride = gridDim.x * blockDim.x;
  for (int e = blockIdx.x * blockDim.x + threadIdx.x; e < NE; e += stride) {
    atomicAdd(&deg_u[uidx[e]], 1.0f);
    atomicAdd(&deg_m[midx[e]], 1.0f);
  }
}

// ---------------------------------------------------------------------------
// fused bidirectional edge aggregation: one wave per edge, lane = feature.
//   agg_m[m] += x_u[u]   (user->movie relation)
//   agg_u[u] += x_m[m]   (movie->user relation)
// ---------------------------------------------------------------------------
__global__ __launch_bounds__(256) void edge_agg_k(const float* __restrict__ xu,
                                                  const float* __restrict__ xm,
                                                  const int* __restrict__ uidx,
                                                  const int* __restrict__ midx,
                                                  float* __restrict__ agg_u,
                                                  float* __restrict__ agg_m) {
  const int lane = threadIdx.x & 63;
  const int wid  = (blockIdx.x * blockDim.x + threadIdx.x) >> 6;
  const int nw   = (gridDim.x * blockDim.x) >> 6;
  for (int e = wid; e < NE; e += nw) {
    const int u = uidx[e];
    const int m = midx[e];
    const float xuv = xu[(size_t)u * D + lane];
    const float xmv = xm[(size_t)m * D + lane];
    atomicAdd(&agg_m[(size_t)m * D + lane], xuv);
    atomicAdd(&agg_u[(size_t)u * D + lane], xmv);
  }
}

// ---------------------------------------------------------------------------
// per-node SAGE update: out = [relu]( (agg/deg) @ Wl + bl + xdst @ Wr )
// wave per node; weight COLUMN `lane` of Wl/Wr held in VGPRs; mean/x values
// broadcast via v_readlane (imm lane index from full unroll).
// ---------------------------------------------------------------------------
__global__ __launch_bounds__(256) void node_update_k(
    const float* __restrict__ agg, const float* __restrict__ deg,
    const float* __restrict__ xdst,
    const float* __restrict__ Wl, const float* __restrict__ bl,
    const float* __restrict__ Wr,
    float* __restrict__ out, int n, int do_relu) {
  const int lane = threadIdx.x & 63;

  float wl[D], wr[D];
#pragma unroll
  for (int k = 0; k < D; ++k) {
    wl[k] = Wl[k * D + lane];   // column `lane`, row k
    wr[k] = Wr[k * D + lane];
  }
  const float b = bl[lane];

  const int wid = (blockIdx.x * blockDim.x + threadIdx.x) >> 6;
  const int nw  = (gridDim.x * blockDim.x) >> 6;

  for (int node = wid; node < n; node += nw) {
    const float dg   = deg[node];
    const float inv  = 1.0f / fmaxf(dg, 1.0f);        // max(cnt,1) semantics
    const float mean = agg[(size_t)node * D + lane] * inv;
    const float xv   = xdst[(size_t)node * D + lane];

    float a0 = 0.f, a1 = 0.f, a2 = 0.f, a3 = 0.f;
#pragma unroll
    for (int k = 0; k < D; k += 2) {
      const float mk0 = __uint_as_float(__builtin_amdgcn_readlane(__float_as_uint(mean), k));
      const float xk0 = __uint_as_float(__builtin_amdgcn_readlane(__float_as_uint(xv),   k));
      const float mk1 = __uint_as_float(__builtin_amdgcn_readlane(__float_as_uint(mean), k + 1));
      const float xk1 = __uint_as_float(__builtin_amdgcn_readlane(__float_as_uint(xv),   k + 1));
      a0 = fmaf(mk0, wl[k],     a0);
      a1 = fmaf(xk0, wr[k],     a1);
      a2 = fmaf(mk1, wl[k + 1], a2);
      a3 = fmaf(xk1, wr[k + 1], a3);
    }
    float acc = b + a0 + a1 + a2 + a3;
    if (do_relu) acc = fmaxf(acc, 0.0f);
    out[(size_t)node * D + lane] = acc;
  }
}

// ---------------------------------------------------------------------------
extern "C" void kernel_launch(void* const* d_in, const int* in_sizes, int n_in,
                              void* d_out, int out_size, void* d_ws, size_t ws_size,
                              hipStream_t stream) {
  const float* x_user  = (const float*)d_in[0];
  const float* x_movie = (const float*)d_in[1];
  const float* Wl1_um = (const float*)d_in[2];
  const float* Wr1_um = (const float*)d_in[3];
  const float* b1_um  = (const float*)d_in[4];
  const float* Wl1_mu = (const float*)d_in[5];
  const float* Wr1_mu = (const float*)d_in[6];
  const float* b1_mu  = (const float*)d_in[7];
  const float* Wl2_um = (const float*)d_in[8];
  const float* Wr2_um = (const float*)d_in[9];
  const float* b2_um  = (const float*)d_in[10];
  const float* Wl2_mu = (const float*)d_in[11];
  const float* Wr2_mu = (const float*)d_in[12];
  const float* b2_mu  = (const float*)d_in[13];
  const int* uidx = (const int*)d_in[14];
  const int* midx = (const int*)d_in[15];

  // workspace layout (all f32): agg_u | agg_m | u1 | m1 | deg_u | deg_m
  char* ws = (char*)d_ws;
  float* agg_u = (float*)ws;  ws += (size_t)NU * D * sizeof(float);
  float* agg_m = (float*)ws;  ws += (size_t)NM * D * sizeof(float);
  float* u1    = (float*)ws;  ws += (size_t)NU * D * sizeof(float);
  float* m1    = (float*)ws;  ws += (size_t)NM * D * sizeof(float);
  float* deg_u = (float*)ws;  ws += (size_t)NU * sizeof(float);
  float* deg_m = (float*)ws;  ws += (size_t)NM * sizeof(float);

  float* u2 = (float*)d_out;                    // users first in concat
  float* m2 = (float*)d_out + (size_t)NU * D;   // then movies

  const dim3 blk(256);

  // ---- zero accumulators + degrees (agg_u/agg_m contiguous; deg_u/deg_m contiguous)
  hipMemsetAsync(agg_u, 0, ((size_t)NU + NM) * D * sizeof(float), stream);
  hipMemsetAsync(deg_u, 0, ((size_t)NU + NM) * sizeof(float), stream);

  degree_k<<<2048, blk, 0, stream>>>(uidx, midx, deg_u, deg_m);

  // ---- layer 1 ----
  edge_agg_k<<<2048, blk, 0, stream>>>(x_user, x_movie, uidx, midx, agg_u, agg_m);
  node_update_k<<<1024, blk, 0, stream>>>(agg_m, deg_m, x_movie,
                                          Wl1_um, b1_um, Wr1_um, m1, NM, 1);
  node_update_k<<<2048, blk, 0, stream>>>(agg_u, deg_u, x_user,
                                          Wl1_mu, b1_mu, Wr1_mu, u1, NU, 1);

  // ---- layer 2 ----
  hipMemsetAsync(agg_u, 0, ((size_t)NU + NM) * D * sizeof(float), stream);
  edge_agg_k<<<2048, blk, 0, stream>>>(u1, m1, uidx, midx, agg_u, agg_m);
  node_update_k<<<1024, blk, 0, stream>>>(agg_m, deg_m, m1,
                                          Wl2_um, b2_um, Wr2_um, m2, NM, 0);
  node_update_k<<<2048, blk, 0, stream>>>(agg_u, deg_u, u1,
                                          Wl2_mu, b2_mu, Wr2_mu, u2, NU, 0);
}

// Round 2
// 2562.690 us; speedup vs baseline: 1.5530x; 1.5530x over previous
//
#include <hip/hip_runtime.h>

#define NU 200000
#define NM 100000
#define NE 4000000
#define D  64

// ---------------------------------------------------------------------------
// int degree histogram for both destinations
// ---------------------------------------------------------------------------
__global__ __launch_bounds__(256) void degree_k(const int* __restrict__ uidx,
                                                const int* __restrict__ midx,
                                                int* __restrict__ deg_u,
                                                int* __restrict__ deg_m) {
  int stride = gridDim.x * blockDim.x;
  for (int e = blockIdx.x * blockDim.x + threadIdx.x; e < NE; e += stride) {
    atomicAdd(&deg_u[uidx[e]], 1);
    atomicAdd(&deg_m[midx[e]], 1);
  }
}

// ---------------------------------------------------------------------------
// single-block exclusive scan: row_ptr[0..n] from deg[0..n-1]
// 1024 threads, each owns a contiguous chunk; Hillis-Steele on chunk sums.
// ---------------------------------------------------------------------------
__global__ __launch_bounds__(1024) void scan_k(const int* __restrict__ deg,
                                               int* __restrict__ rowp, int n) {
  __shared__ int partial[1024];
  const int tid = threadIdx.x;
  const int chunk = (n + 1023) / 1024;
  const int start = tid * chunk;
  const int end = min(start + chunk, n);
  int s = 0;
  for (int i = start; i < end; ++i) s += deg[i];
  partial[tid] = s;
  __syncthreads();
  for (int off = 1; off < 1024; off <<= 1) {
    int v = (tid >= off) ? partial[tid - off] : 0;
    __syncthreads();
    if (tid >= off) partial[tid] += v;
    __syncthreads();
  }
  int run = (tid == 0) ? 0 : partial[tid - 1];
  for (int i = start; i < end; ++i) {
    rowp[i] = run;
    run += deg[i];
  }
  if (tid == 1023) rowp[n] = run;  // total (trailing chunks are empty)
}

// ---------------------------------------------------------------------------
// scatter edges into both adjacency lists (cursor = copy of row_ptr)
// adj_u[user segment] = movie neighbors; adj_m[movie segment] = user neighbors
// ---------------------------------------------------------------------------
__global__ __launch_bounds__(256) void build_adj_k(const int* __restrict__ uidx,
                                                   const int* __restrict__ midx,
                                                   int* __restrict__ cur_u,
                                                   int* __restrict__ cur_m,
                                                   int* __restrict__ adj_u,
                                                   int* __restrict__ adj_m) {
  int stride = gridDim.x * blockDim.x;
  for (int e = blockIdx.x * blockDim.x + threadIdx.x; e < NE; e += stride) {
    const int u = uidx[e];
    const int m = midx[e];
    adj_u[atomicAdd(&cur_u[u], 1)] = m;
    adj_m[atomicAdd(&cur_m[m], 1)] = u;
  }
}

// ---------------------------------------------------------------------------
// CSR gather-aggregate: one wave per destination node, lane = feature.
// Writes the MEAN row (division folded in). adj index is wave-uniform
// -> scalar loads; unroll by 4 for independent in-flight gathers.
// ---------------------------------------------------------------------------
__global__ __launch_bounds__(256) void csr_agg_k(const float* __restrict__ xsrc,
                                                 const int* __restrict__ rowp,
                                                 const int* __restrict__ adj,
                                                 float* __restrict__ mean_out,
                                                 int n) {
  const int lane = threadIdx.x & 63;
  const int wid  = (blockIdx.x * blockDim.x + threadIdx.x) >> 6;
  const int nw   = (gridDim.x * blockDim.x) >> 6;
  for (int node = wid; node < n; node += nw) {
    const int beg = rowp[node];
    const int end = rowp[node + 1];
    float acc = 0.f;
    int j = beg;
    for (; j + 4 <= end; j += 4) {
      const int s0 = adj[j], s1 = adj[j + 1], s2 = adj[j + 2], s3 = adj[j + 3];
      const float v0 = xsrc[(size_t)s0 * D + lane];
      const float v1 = xsrc[(size_t)s1 * D + lane];
      const float v2 = xsrc[(size_t)s2 * D + lane];
      const float v3 = xsrc[(size_t)s3 * D + lane];
      acc += (v0 + v1) + (v2 + v3);
    }
    for (; j < end; ++j) acc += xsrc[(size_t)adj[j] * D + lane];
    const float cnt = (float)(end - beg);
    mean_out[(size_t)node * D + lane] = acc / fmaxf(cnt, 1.0f);
  }
}

// ---------------------------------------------------------------------------
// per-node SAGE update: out = [relu]( mean @ Wl + bl + xdst @ Wr )
// wave per node; weight COLUMN `lane` of Wl/Wr in VGPRs; readlane broadcast.
// ---------------------------------------------------------------------------
__global__ __launch_bounds__(256) void node_update_k(
    const float* __restrict__ mean_in, const float* __restrict__ xdst,
    const float* __restrict__ Wl, const float* __restrict__ bl,
    const float* __restrict__ Wr,
    float* __restrict__ out, int n, int do_relu) {
  const int lane = threadIdx.x & 63;

  float wl[D], wr[D];
#pragma unroll
  for (int k = 0; k < D; ++k) {
    wl[k] = Wl[k * D + lane];   // column `lane`, row k
    wr[k] = Wr[k * D + lane];
  }
  const float b = bl[lane];

  const int wid = (blockIdx.x * blockDim.x + threadIdx.x) >> 6;
  const int nw  = (gridDim.x * blockDim.x) >> 6;

  for (int node = wid; node < n; node += nw) {
    const float mean = mean_in[(size_t)node * D + lane];
    const float xv   = xdst[(size_t)node * D + lane];

    float a0 = 0.f, a1 = 0.f, a2 = 0.f, a3 = 0.f;
#pragma unroll
    for (int k = 0; k < D; k += 2) {
      const float mk0 = __uint_as_float(__builtin_amdgcn_readlane(__float_as_uint(mean), k));
      const float xk0 = __uint_as_float(__builtin_amdgcn_readlane(__float_as_uint(xv),   k));
      const float mk1 = __uint_as_float(__builtin_amdgcn_readlane(__float_as_uint(mean), k + 1));
      const float xk1 = __uint_as_float(__builtin_amdgcn_readlane(__float_as_uint(xv),   k + 1));
      a0 = fmaf(mk0, wl[k],     a0);
      a1 = fmaf(xk0, wr[k],     a1);
      a2 = fmaf(mk1, wl[k + 1], a2);
      a3 = fmaf(xk1, wr[k + 1], a3);
    }
    float acc = b + a0 + a1 + a2 + a3;
    if (do_relu) acc = fmaxf(acc, 0.0f);
    out[(size_t)node * D + lane] = acc;
  }
}

// ---------------------------------------------------------------------------
extern "C" void kernel_launch(void* const* d_in, const int* in_sizes, int n_in,
                              void* d_out, int out_size, void* d_ws, size_t ws_size,
                              hipStream_t stream) {
  const float* x_user  = (const float*)d_in[0];
  const float* x_movie = (const float*)d_in[1];
  const float* Wl1_um = (const float*)d_in[2];
  const float* Wr1_um = (const float*)d_in[3];
  const float* b1_um  = (const float*)d_in[4];
  const float* Wl1_mu = (const float*)d_in[5];
  const float* Wr1_mu = (const float*)d_in[6];
  const float* b1_mu  = (const float*)d_in[7];
  const float* Wl2_um = (const float*)d_in[8];
  const float* Wr2_um = (const float*)d_in[9];
  const float* b2_um  = (const float*)d_in[10];
  const float* Wl2_mu = (const float*)d_in[11];
  const float* Wr2_mu = (const float*)d_in[12];
  const float* b2_mu  = (const float*)d_in[13];
  const int* uidx = (const int*)d_in[14];
  const int* midx = (const int*)d_in[15];

  // workspace layout
  char* ws = (char*)d_ws;
  float* u1    = (float*)ws;  ws += (size_t)NU * D * sizeof(float);
  float* m1    = (float*)ws;  ws += (size_t)NM * D * sizeof(float);
  float* agg_u = (float*)ws;  ws += (size_t)NU * D * sizeof(float);   // mean buffers
  float* agg_m = (float*)ws;  ws += (size_t)NM * D * sizeof(float);
  int* deg_u  = (int*)ws;     ws += (size_t)NU * sizeof(int);
  int* deg_m  = (int*)ws;     ws += (size_t)NM * sizeof(int);
  int* rowp_u = (int*)ws;     ws += ((size_t)NU + 1) * sizeof(int);
  int* rowp_m = (int*)ws;     ws += ((size_t)NM + 1) * sizeof(int);
  int* cur_u  = (int*)ws;     ws += (size_t)NU * sizeof(int);
  int* cur_m  = (int*)ws;     ws += (size_t)NM * sizeof(int);
  int* adj_u  = (int*)ws;     ws += (size_t)NE * sizeof(int);
  int* adj_m  = (int*)ws;     ws += (size_t)NE * sizeof(int);

  float* u2 = (float*)d_out;                    // users first in concat
  float* m2 = (float*)d_out + (size_t)NU * D;   // then movies

  const dim3 blk(256);

  // ---- CSR build (graph identical for both layers) ----
  hipMemsetAsync(deg_u, 0, ((size_t)NU + NM) * sizeof(int), stream);
  degree_k<<<2048, blk, 0, stream>>>(uidx, midx, deg_u, deg_m);
  scan_k<<<1, 1024, 0, stream>>>(deg_u, rowp_u, NU);
  scan_k<<<1, 1024, 0, stream>>>(deg_m, rowp_m, NM);
  hipMemcpyAsync(cur_u, rowp_u, (size_t)NU * sizeof(int), hipMemcpyDeviceToDevice, stream);
  hipMemcpyAsync(cur_m, rowp_m, (size_t)NM * sizeof(int), hipMemcpyDeviceToDevice, stream);
  build_adj_k<<<2048, blk, 0, stream>>>(uidx, midx, cur_u, cur_m, adj_u, adj_m);

  // ---- layer 1 ----
  csr_agg_k<<<1024, blk, 0, stream>>>(x_user, rowp_m, adj_m, agg_m, NM);
  csr_agg_k<<<2048, blk, 0, stream>>>(x_movie, rowp_u, adj_u, agg_u, NU);
  node_update_k<<<1024, blk, 0, stream>>>(agg_m, x_movie, Wl1_um, b1_um, Wr1_um, m1, NM, 1);
  node_update_k<<<2048, blk, 0, stream>>>(agg_u, x_user,  Wl1_mu, b1_mu, Wr1_mu, u1, NU, 1);

  // ---- layer 2 ----
  csr_agg_k<<<1024, blk, 0, stream>>>(u1, rowp_m, adj_m, agg_m, NM);
  csr_agg_k<<<2048, blk, 0, stream>>>(m1, rowp_u, adj_u, agg_u, NU);
  node_update_k<<<1024, blk, 0, stream>>>(agg_m, m1, Wl2_um, b2_um, Wr2_um, m2, NM, 0);
  node_update_k<<<2048, blk, 0, stream>>>(agg_u, u1, Wl2_mu, b2_mu, Wr2_mu, u2, NU, 0);
}

// Round 3
// 1899.673 us; speedup vs baseline: 2.0950x; 1.3490x over previous
//
#include <hip/hip_runtime.h>

#define NU 200000
#define NM 100000
#define NE 4000000
#define D  64

// ---------------------------------------------------------------------------
// fused degree + rank: rank[e] = arrival order of edge e at its destination.
// One atomic pass serves both directions and yields degrees for the scan.
// ---------------------------------------------------------------------------
__global__ __launch_bounds__(256) void rank_k(const int* __restrict__ uidx,
                                              const int* __restrict__ midx,
                                              int* __restrict__ deg_u,
                                              int* __restrict__ deg_m,
                                              int* __restrict__ rank_u,
                                              int* __restrict__ rank_m) {
  int stride = gridDim.x * blockDim.x;
  for (int e = blockIdx.x * blockDim.x + threadIdx.x; e < NE; e += stride) {
    rank_u[e] = atomicAdd(&deg_u[uidx[e]], 1);
    rank_m[e] = atomicAdd(&deg_m[midx[e]], 1);
  }
}

// ---------------------------------------------------------------------------
// single-block exclusive scan: row_ptr[0..n] from deg[0..n-1]
// ---------------------------------------------------------------------------
__global__ __launch_bounds__(1024) void scan_k(const int* __restrict__ deg,
                                               int* __restrict__ rowp, int n) {
  __shared__ int partial[1024];
  const int tid = threadIdx.x;
  const int chunk = (n + 1023) / 1024;
  const int start = tid * chunk;
  const int end = min(start + chunk, n);
  int s = 0;
  for (int i = start; i < end; ++i) s += deg[i];
  partial[tid] = s;
  __syncthreads();
  for (int off = 1; off < 1024; off <<= 1) {
    int v = (tid >= off) ? partial[tid - off] : 0;
    __syncthreads();
    if (tid >= off) partial[tid] += v;
    __syncthreads();
  }
  int run = (tid == 0) ? 0 : partial[tid - 1];
  for (int i = start; i < end; ++i) {
    rowp[i] = run;
    run += deg[i];
  }
  if (tid == 1023) rowp[n] = run;
}

// ---------------------------------------------------------------------------
// atomic-free adjacency scatter: position known from rowp + precomputed rank.
// Stores are independent -> fully pipelined (no L2 round-trip dependency).
// ---------------------------------------------------------------------------
__global__ __launch_bounds__(256) void scatter_k(const int* __restrict__ uidx,
                                                 const int* __restrict__ midx,
                                                 const int* __restrict__ rowp_u,
                                                 const int* __restrict__ rowp_m,
                                                 const int* __restrict__ rank_u,
                                                 const int* __restrict__ rank_m,
                                                 int* __restrict__ adj_u,
                                                 int* __restrict__ adj_m) {
  int stride = gridDim.x * blockDim.x;
  for (int e = blockIdx.x * blockDim.x + threadIdx.x; e < NE; e += stride) {
    const int u = uidx[e];
    const int m = midx[e];
    adj_u[rowp_u[u] + rank_u[e]] = m;
    adj_m[rowp_m[m] + rank_m[e]] = u;
  }
}

// ---------------------------------------------------------------------------
// CSR gather-aggregate: one wave per destination node, lane = feature.
// Writes the MEAN row. Unroll 8 keeps 8 row-gathers in flight.
// ---------------------------------------------------------------------------
__global__ __launch_bounds__(256) void csr_agg_k(const float* __restrict__ xsrc,
                                                 const int* __restrict__ rowp,
                                                 const int* __restrict__ adj,
                                                 float* __restrict__ mean_out,
                                                 int n) {
  const int lane = threadIdx.x & 63;
  const int wid  = (blockIdx.x * blockDim.x + threadIdx.x) >> 6;
  const int nw   = (gridDim.x * blockDim.x) >> 6;
  for (int node = wid; node < n; node += nw) {
    const int beg = rowp[node];
    const int end = rowp[node + 1];
    float acc = 0.f;
    int j = beg;
    for (; j + 8 <= end; j += 8) {
      const int s0 = adj[j],     s1 = adj[j + 1], s2 = adj[j + 2], s3 = adj[j + 3];
      const int s4 = adj[j + 4], s5 = adj[j + 5], s6 = adj[j + 6], s7 = adj[j + 7];
      const float v0 = xsrc[(size_t)s0 * D + lane];
      const float v1 = xsrc[(size_t)s1 * D + lane];
      const float v2 = xsrc[(size_t)s2 * D + lane];
      const float v3 = xsrc[(size_t)s3 * D + lane];
      const float v4 = xsrc[(size_t)s4 * D + lane];
      const float v5 = xsrc[(size_t)s5 * D + lane];
      const float v6 = xsrc[(size_t)s6 * D + lane];
      const float v7 = xsrc[(size_t)s7 * D + lane];
      acc += ((v0 + v1) + (v2 + v3)) + ((v4 + v5) + (v6 + v7));
    }
    for (; j < end; ++j) acc += xsrc[(size_t)adj[j] * D + lane];
    const float cnt = (float)(end - beg);
    mean_out[(size_t)node * D + lane] = acc / fmaxf(cnt, 1.0f);
  }
}

// ---------------------------------------------------------------------------
// per-node SAGE update: out = [relu]( mean @ Wl + bl + xdst @ Wr )
// ---------------------------------------------------------------------------
__global__ __launch_bounds__(256) void node_update_k(
    const float* __restrict__ mean_in, const float* __restrict__ xdst,
    const float* __restrict__ Wl, const float* __restrict__ bl,
    const float* __restrict__ Wr,
    float* __restrict__ out, int n, int do_relu) {
  const int lane = threadIdx.x & 63;

  float wl[D], wr[D];
#pragma unroll
  for (int k = 0; k < D; ++k) {
    wl[k] = Wl[k * D + lane];
    wr[k] = Wr[k * D + lane];
  }
  const float b = bl[lane];

  const int wid = (blockIdx.x * blockDim.x + threadIdx.x) >> 6;
  const int nw  = (gridDim.x * blockDim.x) >> 6;

  for (int node = wid; node < n; node += nw) {
    const float mean = mean_in[(size_t)node * D + lane];
    const float xv   = xdst[(size_t)node * D + lane];

    float a0 = 0.f, a1 = 0.f, a2 = 0.f, a3 = 0.f;
#pragma unroll
    for (int k = 0; k < D; k += 2) {
      const float mk0 = __uint_as_float(__builtin_amdgcn_readlane(__float_as_uint(mean), k));
      const float xk0 = __uint_as_float(__builtin_amdgcn_readlane(__float_as_uint(xv),   k));
      const float mk1 = __uint_as_float(__builtin_amdgcn_readlane(__float_as_uint(mean), k + 1));
      const float xk1 = __uint_as_float(__builtin_amdgcn_readlane(__float_as_uint(xv),   k + 1));
      a0 = fmaf(mk0, wl[k],     a0);
      a1 = fmaf(xk0, wr[k],     a1);
      a2 = fmaf(mk1, wl[k + 1], a2);
      a3 = fmaf(xk1, wr[k + 1], a3);
    }
    float acc = b + a0 + a1 + a2 + a3;
    if (do_relu) acc = fmaxf(acc, 0.0f);
    out[(size_t)node * D + lane] = acc;
  }
}

// ---------------------------------------------------------------------------
extern "C" void kernel_launch(void* const* d_in, const int* in_sizes, int n_in,
                              void* d_out, int out_size, void* d_ws, size_t ws_size,
                              hipStream_t stream) {
  const float* x_user  = (const float*)d_in[0];
  const float* x_movie = (const float*)d_in[1];
  const float* Wl1_um = (const float*)d_in[2];
  const float* Wr1_um = (const float*)d_in[3];
  const float* b1_um  = (const float*)d_in[4];
  const float* Wl1_mu = (const float*)d_in[5];
  const float* Wr1_mu = (const float*)d_in[6];
  const float* b1_mu  = (const float*)d_in[7];
  const float* Wl2_um = (const float*)d_in[8];
  const float* Wr2_um = (const float*)d_in[9];
  const float* b2_um  = (const float*)d_in[10];
  const float* Wl2_mu = (const float*)d_in[11];
  const float* Wr2_mu = (const float*)d_in[12];
  const float* b2_mu  = (const float*)d_in[13];
  const int* uidx = (const int*)d_in[14];
  const int* midx = (const int*)d_in[15];

  // workspace layout
  char* ws = (char*)d_ws;
  float* u1    = (float*)ws;  ws += (size_t)NU * D * sizeof(float);
  float* m1    = (float*)ws;  ws += (size_t)NM * D * sizeof(float);
  float* agg_u = (float*)ws;  ws += (size_t)NU * D * sizeof(float);
  float* agg_m = (float*)ws;  ws += (size_t)NM * D * sizeof(float);
  int* deg_u  = (int*)ws;     ws += (size_t)NU * sizeof(int);
  int* deg_m  = (int*)ws;     ws += (size_t)NM * sizeof(int);
  int* rowp_u = (int*)ws;     ws += ((size_t)NU + 1) * sizeof(int);
  int* rowp_m = (int*)ws;     ws += ((size_t)NM + 1) * sizeof(int);
  int* rank_u = (int*)ws;     ws += (size_t)NE * sizeof(int);
  int* rank_m = (int*)ws;     ws += (size_t)NE * sizeof(int);
  int* adj_u  = (int*)ws;     ws += (size_t)NE * sizeof(int);
  int* adj_m  = (int*)ws;     ws += (size_t)NE * sizeof(int);

  float* u2 = (float*)d_out;                    // users first in concat
  float* m2 = (float*)d_out + (size_t)NU * D;   // then movies

  const dim3 blk(256);

  // ---- CSR build (graph identical for both layers) ----
  hipMemsetAsync(deg_u, 0, ((size_t)NU + NM) * sizeof(int), stream);
  rank_k<<<2048, blk, 0, stream>>>(uidx, midx, deg_u, deg_m, rank_u, rank_m);
  scan_k<<<1, 1024, 0, stream>>>(deg_u, rowp_u, NU);
  scan_k<<<1, 1024, 0, stream>>>(deg_m, rowp_m, NM);
  scatter_k<<<2048, blk, 0, stream>>>(uidx, midx, rowp_u, rowp_m,
                                      rank_u, rank_m, adj_u, adj_m);

  // ---- layer 1 ----
  csr_agg_k<<<1024, blk, 0, stream>>>(x_user, rowp_m, adj_m, agg_m, NM);
  csr_agg_k<<<2048, blk, 0, stream>>>(x_movie, rowp_u, adj_u, agg_u, NU);
  node_update_k<<<1024, blk, 0, stream>>>(agg_m, x_movie, Wl1_um, b1_um, Wr1_um, m1, NM, 1);
  node_update_k<<<2048, blk, 0, stream>>>(agg_u, x_user,  Wl1_mu, b1_mu, Wr1_mu, u1, NU, 1);

  // ---- layer 2 ----
  csr_agg_k<<<1024, blk, 0, stream>>>(u1, rowp_m, adj_m, agg_m, NM);
  csr_agg_k<<<2048, blk, 0, stream>>>(m1, rowp_u, adj_u, agg_u, NU);
  node_update_k<<<1024, blk, 0, stream>>>(agg_m, m1, Wl2_um, b2_um, Wr2_um, m2, NM, 0);
  node_update_k<<<2048, blk, 0, stream>>>(agg_u, u1, Wl2_mu, b2_mu, Wr2_mu, u2, NU, 0);
}

// Round 4
// 1697.083 us; speedup vs baseline: 2.3451x; 1.1194x over previous
//
#include <hip/hip_runtime.h>

#define NU 200000
#define NM 100000
#define NE 4000000
#define D  64
#define NC 8   // privatized histogram copies

// ---------------------------------------------------------------------------
// privatized degree+rank: rank[e] = arrival order within copy c=(e>>8)&7.
// 8x fewer concurrent RMWs per cache line than a single histogram.
// ---------------------------------------------------------------------------
__global__ __launch_bounds__(256) void rank2_k(const int* __restrict__ uidx,
                                               const int* __restrict__ midx,
                                               int* __restrict__ hist_u,
                                               int* __restrict__ hist_m,
                                               int* __restrict__ rank_u,
                                               int* __restrict__ rank_m) {
  int stride = gridDim.x * blockDim.x;
  for (int e = blockIdx.x * blockDim.x + threadIdx.x; e < NE; e += stride) {
    const int c = (e >> 8) & (NC - 1);
    rank_u[e] = atomicAdd(&hist_u[c * NU + uidx[e]], 1);
    rank_m[e] = atomicAdd(&hist_m[c * NM + midx[e]], 1);
  }
}

// ---------------------------------------------------------------------------
// per-node: turn per-copy counts into per-copy exclusive prefixes, emit degree
// ---------------------------------------------------------------------------
__global__ __launch_bounds__(256) void reduce_k(int* __restrict__ hist_u,
                                                int* __restrict__ hist_m,
                                                int* __restrict__ deg_u,
                                                int* __restrict__ deg_m) {
  const int v = blockIdx.x * blockDim.x + threadIdx.x;
  if (v < NU) {
    int t = 0;
#pragma unroll
    for (int c = 0; c < NC; ++c) {
      const int h = hist_u[c * NU + v];
      hist_u[c * NU + v] = t;
      t += h;
    }
    deg_u[v] = t;
  } else if (v < NU + NM) {
    const int w = v - NU;
    int t = 0;
#pragma unroll
    for (int c = 0; c < NC; ++c) {
      const int h = hist_m[c * NM + w];
      hist_m[c * NM + w] = t;
      t += h;
    }
    deg_m[w] = t;
  }
}

// ---------------------------------------------------------------------------
// two single-block exclusive scans in one launch (block 0: users, 1: movies)
// ---------------------------------------------------------------------------
__global__ __launch_bounds__(1024) void scan2_k(const int* __restrict__ deg_u,
                                                int* __restrict__ rowp_u,
                                                const int* __restrict__ deg_m,
                                                int* __restrict__ rowp_m) {
  const int* deg = (blockIdx.x == 0) ? deg_u : deg_m;
  int* rowp      = (blockIdx.x == 0) ? rowp_u : rowp_m;
  const int n    = (blockIdx.x == 0) ? NU : NM;

  __shared__ int partial[1024];
  const int tid = threadIdx.x;
  const int chunk = (n + 1023) / 1024;
  const int start = tid * chunk;
  const int end = min(start + chunk, n);
  int s = 0;
  for (int i = start; i < end; ++i) s += deg[i];
  partial[tid] = s;
  __syncthreads();
  for (int off = 1; off < 1024; off <<= 1) {
    int v = (tid >= off) ? partial[tid - off] : 0;
    __syncthreads();
    if (tid >= off) partial[tid] += v;
    __syncthreads();
  }
  int run = (tid == 0) ? 0 : partial[tid - 1];
  for (int i = start; i < end; ++i) {
    rowp[i] = run;
    run += deg[i];
  }
  if (tid == 1023) rowp[n] = partial[1023];
}

// ---------------------------------------------------------------------------
// fold rowp into the per-copy prefixes: hist[c][v] += rowp[v]
// afterwards scatter needs only ONE random gather per direction.
// ---------------------------------------------------------------------------
__global__ __launch_bounds__(256) void fold_k(int* __restrict__ hist_u,
                                              int* __restrict__ hist_m,
                                              const int* __restrict__ rowp_u,
                                              const int* __restrict__ rowp_m) {
  const int v = blockIdx.x * blockDim.x + threadIdx.x;
  if (v < NU) {
    const int r = rowp_u[v];
#pragma unroll
    for (int c = 0; c < NC; ++c) hist_u[c * NU + v] += r;
  } else if (v < NU + NM) {
    const int w = v - NU;
    const int r = rowp_m[w];
#pragma unroll
    for (int c = 0; c < NC; ++c) hist_m[c * NM + w] += r;
  }
}

// ---------------------------------------------------------------------------
// atomic-free adjacency scatter: position = hist_fold[c][dst] + rank[e]
// ---------------------------------------------------------------------------
__global__ __launch_bounds__(256) void scatter2_k(const int* __restrict__ uidx,
                                                  const int* __restrict__ midx,
                                                  const int* __restrict__ hist_u,
                                                  const int* __restrict__ hist_m,
                                                  const int* __restrict__ rank_u,
                                                  const int* __restrict__ rank_m,
                                                  int* __restrict__ adj_u,
                                                  int* __restrict__ adj_m) {
  int stride = gridDim.x * blockDim.x;
  for (int e = blockIdx.x * blockDim.x + threadIdx.x; e < NE; e += stride) {
    const int c = (e >> 8) & (NC - 1);
    const int u = uidx[e];
    const int m = midx[e];
    adj_u[hist_u[c * NU + u] + rank_u[e]] = m;
    adj_m[hist_m[c * NM + m] + rank_m[e]] = u;
  }
}

// ---------------------------------------------------------------------------
// CSR gather-aggregate for one node (wave-cooperative, lane = feature)
// ---------------------------------------------------------------------------
__device__ __forceinline__ void agg_one(const float* __restrict__ xsrc,
                                        const int* __restrict__ rowp,
                                        const int* __restrict__ adj,
                                        float* __restrict__ mean_out,
                                        int node, int lane) {
  const int beg = rowp[node];
  const int end = rowp[node + 1];
  float acc = 0.f;
  int j = beg;
  for (; j + 8 <= end; j += 8) {
    const int s0 = adj[j],     s1 = adj[j + 1], s2 = adj[j + 2], s3 = adj[j + 3];
    const int s4 = adj[j + 4], s5 = adj[j + 5], s6 = adj[j + 6], s7 = adj[j + 7];
    const float v0 = xsrc[(size_t)s0 * D + lane];
    const float v1 = xsrc[(size_t)s1 * D + lane];
    const float v2 = xsrc[(size_t)s2 * D + lane];
    const float v3 = xsrc[(size_t)s3 * D + lane];
    const float v4 = xsrc[(size_t)s4 * D + lane];
    const float v5 = xsrc[(size_t)s5 * D + lane];
    const float v6 = xsrc[(size_t)s6 * D + lane];
    const float v7 = xsrc[(size_t)s7 * D + lane];
    acc += ((v0 + v1) + (v2 + v3)) + ((v4 + v5) + (v6 + v7));
  }
  for (; j < end; ++j) acc += xsrc[(size_t)adj[j] * D + lane];
  const float cnt = (float)(end - beg);
  mean_out[(size_t)node * D + lane] = acc / fmaxf(cnt, 1.0f);
}

// both directions in one launch: first 1/3 of waves -> movies, rest -> users
__global__ __launch_bounds__(256) void csr_both_k(const float* __restrict__ xu,
                                                  const float* __restrict__ xm,
                                                  const int* __restrict__ rowp_u,
                                                  const int* __restrict__ rowp_m,
                                                  const int* __restrict__ adj_u,
                                                  const int* __restrict__ adj_m,
                                                  float* __restrict__ agg_u,
                                                  float* __restrict__ agg_m) {
  const int lane = threadIdx.x & 63;
  const int wid  = (blockIdx.x * blockDim.x + threadIdx.x) >> 6;
  const int W    = (gridDim.x * blockDim.x) >> 6;
  const int WM   = W / 3;
  if (wid < WM) {
    for (int node = wid; node < NM; node += WM)
      agg_one(xu, rowp_m, adj_m, agg_m, node, lane);
  } else {
    const int uw = wid - WM, UW = W - WM;
    for (int node = uw; node < NU; node += UW)
      agg_one(xm, rowp_u, adj_u, agg_u, node, lane);
  }
}

// ---------------------------------------------------------------------------
// per-node SAGE update, both relations in one launch.
// out = [relu]( mean @ Wl + bl + xdst @ Wr ); weight column in VGPRs.
// ---------------------------------------------------------------------------
__global__ __launch_bounds__(256) void node_both_k(
    const float* __restrict__ agg_u, const float* __restrict__ agg_m,
    const float* __restrict__ xu,    const float* __restrict__ xm,
    const float* __restrict__ Wl_mu, const float* __restrict__ b_mu,
    const float* __restrict__ Wr_mu,
    const float* __restrict__ Wl_um, const float* __restrict__ b_um,
    const float* __restrict__ Wr_um,
    float* __restrict__ out_u, float* __restrict__ out_m, int do_relu) {
  const int lane = threadIdx.x & 63;
  const int wid  = (blockIdx.x * blockDim.x + threadIdx.x) >> 6;
  const int W    = (gridDim.x * blockDim.x) >> 6;
  const int WM   = W / 3;

  const float *Wl, *Wr, *bias, *mean_in, *xdst;
  float* out;
  int n, w0, nw;
  if (wid < WM) {   // movies: relation user->movie
    Wl = Wl_um; Wr = Wr_um; bias = b_um;
    mean_in = agg_m; xdst = xm; out = out_m; n = NM; w0 = wid; nw = WM;
  } else {          // users: relation movie->user
    Wl = Wl_mu; Wr = Wr_mu; bias = b_mu;
    mean_in = agg_u; xdst = xu; out = out_u; n = NU; w0 = wid - WM; nw = W - WM;
  }

  float wl[D], wr[D];
#pragma unroll
  for (int k = 0; k < D; ++k) {
    wl[k] = Wl[k * D + lane];   // column `lane`, row k
    wr[k] = Wr[k * D + lane];
  }
  const float b = bias[lane];

  for (int node = w0; node < n; node += nw) {
    const float mean = mean_in[(size_t)node * D + lane];
    const float xv   = xdst[(size_t)node * D + lane];

    float a0 = 0.f, a1 = 0.f, a2 = 0.f, a3 = 0.f;
#pragma unroll
    for (int k = 0; k < D; k += 2) {
      const float mk0 = __uint_as_float(__builtin_amdgcn_readlane(__float_as_uint(mean), k));
      const float xk0 = __uint_as_float(__builtin_amdgcn_readlane(__float_as_uint(xv),   k));
      const float mk1 = __uint_as_float(__builtin_amdgcn_readlane(__float_as_uint(mean), k + 1));
      const float xk1 = __uint_as_float(__builtin_amdgcn_readlane(__float_as_uint(xv),   k + 1));
      a0 = fmaf(mk0, wl[k],     a0);
      a1 = fmaf(xk0, wr[k],     a1);
      a2 = fmaf(mk1, wl[k + 1], a2);
      a3 = fmaf(xk1, wr[k + 1], a3);
    }
    float acc = b + a0 + a1 + a2 + a3;
    if (do_relu) acc = fmaxf(acc, 0.0f);
    out[(size_t)node * D + lane] = acc;
  }
}

// ---------------------------------------------------------------------------
extern "C" void kernel_launch(void* const* d_in, const int* in_sizes, int n_in,
                              void* d_out, int out_size, void* d_ws, size_t ws_size,
                              hipStream_t stream) {
  const float* x_user  = (const float*)d_in[0];
  const float* x_movie = (const float*)d_in[1];
  const float* Wl1_um = (const float*)d_in[2];
  const float* Wr1_um = (const float*)d_in[3];
  const float* b1_um  = (const float*)d_in[4];
  const float* Wl1_mu = (const float*)d_in[5];
  const float* Wr1_mu = (const float*)d_in[6];
  const float* b1_mu  = (const float*)d_in[7];
  const float* Wl2_um = (const float*)d_in[8];
  const float* Wr2_um = (const float*)d_in[9];
  const float* b2_um  = (const float*)d_in[10];
  const float* Wl2_mu = (const float*)d_in[11];
  const float* Wr2_mu = (const float*)d_in[12];
  const float* b2_mu  = (const float*)d_in[13];
  const int* uidx = (const int*)d_in[14];
  const int* midx = (const int*)d_in[15];

  // ---- workspace layout (aliasing: rank lives in u1, hist lives in m1;
  //      both are dead before u1/m1 are first written) ----
  char* ws = (char*)d_ws;
  float* u1    = (float*)ws;  ws += (size_t)NU * D * sizeof(float);   // 51.2 MB
  float* m1    = (float*)ws;  ws += (size_t)NM * D * sizeof(float);   // 25.6 MB
  float* agg_u = (float*)ws;  ws += (size_t)NU * D * sizeof(float);
  float* agg_m = (float*)ws;  ws += (size_t)NM * D * sizeof(float);
  int* deg_u  = (int*)ws;     ws += (size_t)NU * sizeof(int);
  int* deg_m  = (int*)ws;     ws += (size_t)NM * sizeof(int);
  int* rowp_u = (int*)ws;     ws += ((size_t)NU + 1) * sizeof(int);
  int* rowp_m = (int*)ws;     ws += ((size_t)NM + 1) * sizeof(int);
  int* adj_u  = (int*)ws;     ws += (size_t)NE * sizeof(int);
  int* adj_m  = (int*)ws;     ws += (size_t)NE * sizeof(int);

  int* rank_u = (int*)u1;                 // 16 MB \ inside u1 (51.2 MB)
  int* rank_m = rank_u + NE;              // 16 MB /
  int* hist_u = (int*)m1;                 // 6.4 MB \ inside m1 (25.6 MB)
  int* hist_m = hist_u + (size_t)NC * NU; // 3.2 MB /

  float* u2 = (float*)d_out;
  float* m2 = (float*)d_out + (size_t)NU * D;

  const dim3 blk(256);
  const int NODE_BLKS = (NU + NM + 255) / 256;

  // ---- CSR build ----
  hipMemsetAsync(hist_u, 0, (size_t)NC * (NU + NM) * sizeof(int), stream);
  rank2_k<<<2048, blk, 0, stream>>>(uidx, midx, hist_u, hist_m, rank_u, rank_m);
  reduce_k<<<NODE_BLKS, blk, 0, stream>>>(hist_u, hist_m, deg_u, deg_m);
  scan2_k<<<2, 1024, 0, stream>>>(deg_u, rowp_u, deg_m, rowp_m);
  fold_k<<<NODE_BLKS, blk, 0, stream>>>(hist_u, hist_m, rowp_u, rowp_m);
  scatter2_k<<<2048, blk, 0, stream>>>(uidx, midx, hist_u, hist_m,
                                       rank_u, rank_m, adj_u, adj_m);

  // ---- layer 1 ----
  csr_both_k<<<3072, blk, 0, stream>>>(x_user, x_movie, rowp_u, rowp_m,
                                       adj_u, adj_m, agg_u, agg_m);
  node_both_k<<<3072, blk, 0, stream>>>(agg_u, agg_m, x_user, x_movie,
                                        Wl1_mu, b1_mu, Wr1_mu,
                                        Wl1_um, b1_um, Wr1_um,
                                        u1, m1, 1);

  // ---- layer 2 ----
  csr_both_k<<<3072, blk, 0, stream>>>(u1, m1, rowp_u, rowp_m,
                                       adj_u, adj_m, agg_u, agg_m);
  node_both_k<<<3072, blk, 0, stream>>>(agg_u, agg_m, u1, m1,
                                        Wl2_mu, b2_mu, Wr2_mu,
                                        Wl2_um, b2_um, Wr2_um,
                                        u2, m2, 0);
}